// Round 10
// baseline (345.106 us; speedup 1.0000x reference)
//
#include <hip/hip_runtime.h>

// InnerSelfAttention (sliding-window causal, WIN=256, unscaled QK^T) for MI355X.
// R5 experiment, 3rd submission (R8/R9 benches died at GPU acquire — no data):
//   isolate the 380MB phantom WRITE_SIZE. Single variable vs R4:
//   staging reverted to R1's reg-staged path (global_load_lds removed entirely;
//   R1 control measured 16MB WRITE with this store pattern + reg staging).
//   Grid order reverted to R3 natural (24,32) (FETCH 137MB vs swizzle's 215MB).
//   Kept from R4: fused QKV, V coalesced [B,H,S,D], attn LDS V-transpose,
//   out_gemm BM=64 2/CU.
// B=2 S=2048 E=1024 H=16 D=64 WIN=256.

typedef __bf16 bf16x8 __attribute__((ext_vector_type(8)));
typedef short s16x8 __attribute__((ext_vector_type(8)));
typedef float f32x4 __attribute__((ext_vector_type(4)));
typedef unsigned short u16;
typedef unsigned long long u64;

#define DEV __device__ __forceinline__

DEV u16 f2bf(float f) {  // RNE float->bf16
  unsigned u = __builtin_bit_cast(unsigned, f);
  u += 0x7FFFu + ((u >> 16) & 1u);
  return (u16)(u >> 16);
}
DEV float bf2f(u16 h) {
  unsigned u = ((unsigned)h) << 16;
  return __builtin_bit_cast(float, u);
}

#define MFMA16(a, b, c) __builtin_amdgcn_mfma_f32_16x16x32_bf16((a), (b), (c), 0, 0, 0)

// ---------------- fused convert / split kernel ----------------
__global__ __launch_bounds__(256) void cvt_all(
    const float* __restrict__ x, const float* __restrict__ Wq,
    const float* __restrict__ Wk, const float* __restrict__ Wv,
    const float* __restrict__ Wo, u16* __restrict__ xh, u16* __restrict__ xl,
    u16* __restrict__ wh, u16* __restrict__ wl, u16* __restrict__ woh) {
  for (int i = blockIdx.x * 256 + threadIdx.x; i < 2097152;
       i += gridDim.x * 256) {
    const float* src;
    u16 *dh, *dl = nullptr;
    int off;
    bool sp;
    if (i < 1048576) {
      src = x; off = i; dh = xh; dl = xl; sp = true;
    } else {
      int j = i - 1048576;
      int r = j >> 18;
      off = j & 262143;
      if (r == 0)      { src = Wq; dh = wh;           dl = wl;           sp = true; }
      else if (r == 1) { src = Wk; dh = wh + 1048576; dl = wl + 1048576; sp = true; }
      else if (r == 2) { src = Wv; dh = wh + 2097152; sp = false; }
      else             { src = Wo; dh = woh;          sp = false; }
    }
    f32x4 v = ((const f32x4*)src)[off];
    u64 ph = 0, pl = 0;
#pragma unroll
    for (int c = 0; c < 4; ++c) {
      u16 h = f2bf(v[c]);
      ph |= ((u64)h) << (16 * c);
      u16 l = f2bf(v[c] - bf2f(h));
      pl |= ((u64)l) << (16 * c);
    }
    ((u64*)dh)[off] = ph;
    if (sp) ((u64*)dl)[off] = pl;
  }
}

// ---------------- fused QKV GEMM (reg-staged, padded LDS) -------------------
// C[4096][3072] = x[4096][1024] . W[3072][1024]^T, bf16x3 for Q/K regions,
// single bf16 for V region. All outputs written coalesced in [B,H,S,D].
__global__ __launch_bounds__(256, 3) void qkv_gemm(
    const u16* __restrict__ Xh, const u16* __restrict__ Xl,
    const u16* __restrict__ Wh, const u16* __restrict__ Wl,
    u16* __restrict__ qh, u16* __restrict__ ql, u16* __restrict__ kh,
    u16* __restrict__ kl, u16* __restrict__ vh) {
  constexpr int BKP = 40;  // 32 + 8 pad (R1-proven: 80B row stride, 2-way alias)
  __shared__ u16 sAh[128][BKP], sAl[128][BKP];
  __shared__ u16 sBh[128][BKP], sBl[128][BKP];
  const int tid = threadIdx.x, lane = tid & 63, w = tid >> 6;
  const int lr = lane & 15, lg = lane >> 4;
  const int wr = w >> 1, wc = w & 1;
  const int m0 = blockIdx.y * 128, n0 = blockIdx.x * 128;  // R3 natural order
  const int region = n0 >> 10;  // 0=Q 1=K 2=V
  const bool split = region < 2;

  f32x4 acc[4][4];
#pragma unroll
  for (int i = 0; i < 4; ++i)
#pragma unroll
    for (int j = 0; j < 4; ++j)
#pragma unroll
      for (int e = 0; e < 4; ++e) acc[i][j][e] = 0.f;

  for (int k0 = 0; k0 < 1024; k0 += 32) {
// reg-staged 128x32 tiles (R1-proven path; no global_load_lds)
#pragma unroll
    for (int c = 0; c < 2; ++c) {
      int cid = c * 256 + tid;
      int row = cid >> 2, col8 = (cid & 3) * 8;
      size_t aoff = (size_t)(m0 + row) * 1024 + k0 + col8;
      size_t boff = (size_t)(n0 + row) * 1024 + k0 + col8;
      *(s16x8*)&sAh[row][col8] = *(const s16x8*)&Xh[aoff];
      *(s16x8*)&sBh[row][col8] = *(const s16x8*)&Wh[boff];
      if (split) {
        *(s16x8*)&sAl[row][col8] = *(const s16x8*)&Xl[aoff];
        *(s16x8*)&sBl[row][col8] = *(const s16x8*)&Wl[boff];
      }
    }
    __syncthreads();

    bf16x8 fah[4], fbh[4], fal[4], fbl[4];
#pragma unroll
    for (int f = 0; f < 4; ++f) {
      fah[f] = *(const bf16x8*)&sAh[wr * 64 + f * 16 + lr][lg * 8];
      fbh[f] = *(const bf16x8*)&sBh[wc * 64 + f * 16 + lr][lg * 8];
    }
    if (split) {
#pragma unroll
      for (int f = 0; f < 4; ++f) {
        fal[f] = *(const bf16x8*)&sAl[wr * 64 + f * 16 + lr][lg * 8];
        fbl[f] = *(const bf16x8*)&sBl[wc * 64 + f * 16 + lr][lg * 8];
      }
#pragma unroll
      for (int i = 0; i < 4; ++i)
#pragma unroll
        for (int j = 0; j < 4; ++j) {
          acc[i][j] = MFMA16(fah[i], fbh[j], acc[i][j]);
          acc[i][j] = MFMA16(fah[i], fbl[j], acc[i][j]);
          acc[i][j] = MFMA16(fal[i], fbh[j], acc[i][j]);
        }
    } else {
#pragma unroll
      for (int i = 0; i < 4; ++i)
#pragma unroll
        for (int j = 0; j < 4; ++j)
          acc[i][j] = MFMA16(fah[i], fbh[j], acc[i][j]);
    }
    __syncthreads();
  }

// epilogue. C layout (m89): col = lane&15, row = (lane>>4)*4 + e
#pragma unroll
  for (int i = 0; i < 4; ++i)
#pragma unroll
    for (int j = 0; j < 4; ++j)
#pragma unroll
      for (int e = 0; e < 4; ++e) {
        float v = acc[i][j][e];
        int mm = m0 + wr * 64 + i * 16 + lg * 4 + e;
        int nl = (n0 & 1023) + wc * 64 + j * 16 + lr;
        int bb = mm >> 11, ss = mm & 2047, hh = nl >> 6, dd = nl & 63;
        size_t idx = ((size_t)(bb * 16 + hh) * 2048 + ss) * 64 + dd;
        if (region == 0) {
          u16 h = f2bf(v);
          qh[idx] = h;
          ql[idx] = f2bf(v - bf2f(h));
        } else if (region == 1) {
          u16 h = f2bf(v);
          kh[idx] = h;
          kl[idx] = f2bf(v - bf2f(h));
        } else {
          vh[idx] = f2bf(v);
        }
      }
}

// ---------------- O-projection GEMM: BM=64, BN=128, reg-staged --------------
__global__ __launch_bounds__(256, 2) void out_gemm(const u16* __restrict__ ctx,
                                                   const u16* __restrict__ Wo,
                                                   const float* __restrict__ bias,
                                                   float* __restrict__ Of) {
  constexpr int BKP = 40;
  __shared__ u16 sA[64][BKP], sB[128][BKP];
  const int tid = threadIdx.x, lane = tid & 63, w = tid >> 6;
  const int lr = lane & 15, lg = lane >> 4;
  const int m0 = blockIdx.y * 64, n0 = blockIdx.x * 128;

  f32x4 acc[4][2];
#pragma unroll
  for (int i = 0; i < 4; ++i)
#pragma unroll
    for (int j = 0; j < 2; ++j)
#pragma unroll
      for (int e = 0; e < 4; ++e) acc[i][j][e] = 0.f;

  for (int k0 = 0; k0 < 1024; k0 += 32) {
    {  // A 64x32: 256 chunks, 1/thread
      int row = tid >> 2, col8 = (tid & 3) * 8;
      *(s16x8*)&sA[row][col8] =
          *(const s16x8*)&ctx[(size_t)(m0 + row) * 1024 + k0 + col8];
    }
#pragma unroll
    for (int c = 0; c < 2; ++c) {  // B 128x32
      int cid = c * 256 + tid;
      int row = cid >> 2, col8 = (cid & 3) * 8;
      *(s16x8*)&sB[row][col8] =
          *(const s16x8*)&Wo[(size_t)(n0 + row) * 1024 + k0 + col8];
    }
    __syncthreads();
    bf16x8 fa[4], fb[2];
#pragma unroll
    for (int f = 0; f < 4; ++f)
      fa[f] = *(const bf16x8*)&sA[f * 16 + lr][lg * 8];
#pragma unroll
    for (int j = 0; j < 2; ++j)
      fb[j] = *(const bf16x8*)&sB[w * 32 + j * 16 + lr][lg * 8];
#pragma unroll
    for (int i = 0; i < 4; ++i)
#pragma unroll
      for (int j = 0; j < 2; ++j) acc[i][j] = MFMA16(fa[i], fb[j], acc[i][j]);
    __syncthreads();
  }
#pragma unroll
  for (int i = 0; i < 4; ++i)
#pragma unroll
    for (int j = 0; j < 2; ++j)
#pragma unroll
      for (int e = 0; e < 4; ++e) {
        int mm = m0 + i * 16 + lg * 4 + e;
        int nn = n0 + w * 32 + j * 16 + lr;
        Of[(size_t)mm * 1024 + nn] = acc[i][j][e] + bias[nn];
      }
}

// ---------------- flash attention, 64-query blocks, 64-key tiles ------------
// V arrives [B,H,S,D]; transposed into sVT[d][key] via LDS scatter at staging.
__global__ __launch_bounds__(256) void attn_kernel(
    const u16* __restrict__ qh, const u16* __restrict__ ql,
    const u16* __restrict__ kh, const u16* __restrict__ kl,
    const u16* __restrict__ vh, u16* __restrict__ ctx) {
  const int qt = blockIdx.x, hd = blockIdx.y, b = blockIdx.z;
  const int q0 = qt * 64;
  const int bh = b * 16 + hd;
  const int tid = threadIdx.x;
  const int lane = tid & 63, w = tid >> 6;
  const int lr = lane & 15, lg = lane >> 4;

  __shared__ u16 sKh[64][72];   // [key][d], 144B rows -> 2-way alias
  __shared__ u16 sKl[64][72];
  __shared__ u16 sVT[64][72];   // [d][key]
  __shared__ u16 sP[4][16][72]; // per-wave P tile [q][key]

  bf16x8 qfh[2], qfl[2];
  const size_t qbase = ((size_t)bh * 2048 + q0 + w * 16 + lr) * 64;
#pragma unroll
  for (int ks = 0; ks < 2; ++ks) {
    qfh[ks] = *(const bf16x8*)&qh[qbase + ks * 32 + lg * 8];
    qfl[ks] = *(const bf16x8*)&ql[qbase + ks * 32 + lg * 8];
  }

  float mrow[4], lrow[4];
  f32x4 cf[4];
#pragma unroll
  for (int e = 0; e < 4; ++e) { mrow[e] = -__builtin_inff(); lrow[e] = 0.f; }
#pragma unroll
  for (int nd = 0; nd < 4; ++nd)
#pragma unroll
    for (int e = 0; e < 4; ++e) cf[nd][e] = 0.f;

  const int t0 = (qt >= 4) ? qt - 4 : 0;
  for (int t = t0; t <= qt; ++t) {
    const int k0 = t * 64;
#pragma unroll
    for (int c = 0; c < 2; ++c) {
      int cid = c * 256 + tid;
      int row = cid >> 3, col8 = (cid & 7) * 8;
      size_t kidx = ((size_t)bh * 2048 + k0 + row) * 64 + col8;
      *(s16x8*)&sKh[row][col8] = *(const s16x8*)&kh[kidx];
      *(s16x8*)&sKl[row][col8] = *(const s16x8*)&kl[kidx];
      s16x8 vv = *(const s16x8*)&vh[kidx];  // coalesced V row read
#pragma unroll
      for (int j = 0; j < 8; ++j)           // LDS transpose scatter
        sVT[col8 + j][row] = (u16)vv[j];
    }
    __syncthreads();

    f32x4 sc[4];
#pragma unroll
    for (int nf = 0; nf < 4; ++nf)
#pragma unroll
      for (int e = 0; e < 4; ++e) sc[nf][e] = 0.f;
#pragma unroll
    for (int ks = 0; ks < 2; ++ks)
#pragma unroll
      for (int nf = 0; nf < 4; ++nf) {
        bf16x8 kbh = *(const bf16x8*)&sKh[nf * 16 + lr][ks * 32 + lg * 8];
        bf16x8 kbl = *(const bf16x8*)&sKl[nf * 16 + lr][ks * 32 + lg * 8];
        sc[nf] = MFMA16(qfh[ks], kbh, sc[nf]);
        sc[nf] = MFMA16(qfh[ks], kbl, sc[nf]);
        sc[nf] = MFMA16(qfl[ks], kbh, sc[nf]);
      }

    const bool masked = (k0 < q0 - 192) || (k0 >= q0);
    if (masked) {
#pragma unroll
      for (int nf = 0; nf < 4; ++nf) {
        int key = k0 + nf * 16 + lr;
#pragma unroll
        for (int e = 0; e < 4; ++e) {
          int qi = q0 + w * 16 + lg * 4 + e;
          if (key > qi || key + 256 <= qi) sc[nf][e] = -__builtin_inff();
        }
      }
    }

    float rm[4];
#pragma unroll
    for (int e = 0; e < 4; ++e)
      rm[e] = fmaxf(fmaxf(sc[0][e], sc[1][e]), fmaxf(sc[2][e], sc[3][e]));
#pragma unroll
    for (int off = 1; off < 16; off <<= 1)
#pragma unroll
      for (int e = 0; e < 4; ++e) rm[e] = fmaxf(rm[e], __shfl_xor(rm[e], off));

    float alpha[4], mu[4];
#pragma unroll
    for (int e = 0; e < 4; ++e) {
      float mn = fmaxf(mrow[e], rm[e]);
      bool ninf = (mn == -__builtin_inff());
      mu[e] = ninf ? 0.f : mn;
      alpha[e] = ninf ? 1.f : __expf(mrow[e] - mn);
      mrow[e] = mn;
    }
    float p[4][4], rs[4];
#pragma unroll
    for (int nf = 0; nf < 4; ++nf)
#pragma unroll
      for (int e = 0; e < 4; ++e) p[nf][e] = __expf(sc[nf][e] - mu[e]);
#pragma unroll
    for (int e = 0; e < 4; ++e) rs[e] = p[0][e] + p[1][e] + p[2][e] + p[3][e];
#pragma unroll
    for (int off = 1; off < 16; off <<= 1)
#pragma unroll
      for (int e = 0; e < 4; ++e) rs[e] += __shfl_xor(rs[e], off);
#pragma unroll
    for (int e = 0; e < 4; ++e) lrow[e] = lrow[e] * alpha[e] + rs[e];
#pragma unroll
    for (int nd = 0; nd < 4; ++nd)
#pragma unroll
      for (int e = 0; e < 4; ++e) cf[nd][e] *= alpha[e];

#pragma unroll
    for (int nf = 0; nf < 4; ++nf)
#pragma unroll
      for (int e = 0; e < 4; ++e)
        sP[w][lg * 4 + e][nf * 16 + lr] = f2bf(p[nf][e]);

#pragma unroll
    for (int ks = 0; ks < 2; ++ks) {
      bf16x8 pa = *(const bf16x8*)&sP[w][lr][ks * 32 + lg * 8];
#pragma unroll
      for (int nd = 0; nd < 4; ++nd) {
        bf16x8 vb = *(const bf16x8*)&sVT[nd * 16 + lr][ks * 32 + lg * 8];
        cf[nd] = MFMA16(pa, vb, cf[nd]);
      }
    }
    __syncthreads();
  }

#pragma unroll
  for (int nd = 0; nd < 4; ++nd)
#pragma unroll
    for (int e = 0; e < 4; ++e) {
      float v = cf[nd][e] / lrow[e];
      size_t o = ((size_t)(b * 2048 + q0 + w * 16 + lg * 4 + e)) * 1024 +
                 hd * 64 + nd * 16 + lr;
      ctx[o] = f2bf(v);
    }
}

// ---------------- launch ----------------
extern "C" void kernel_launch(void* const* d_in, const int* in_sizes, int n_in,
                              void* d_out, int out_size, void* d_ws, size_t ws_size,
                              hipStream_t stream) {
  (void)in_sizes; (void)n_in; (void)out_size; (void)ws_size;
  const float* x  = (const float*)d_in[0];
  const float* Wq = (const float*)d_in[1];
  const float* Wk = (const float*)d_in[2];
  const float* Wv = (const float*)d_in[3];
  const float* Wo = (const float*)d_in[4];
  const float* bo = (const float*)d_in[5];
  float* out = (float*)d_out;
  char* ws = (char*)d_ws;

  constexpr size_t MB = 1048576;
  u16* xh  = (u16*)(ws + 0 * MB);
  u16* xl  = (u16*)(ws + 8 * MB);
  u16* qh  = (u16*)(ws + 16 * MB);
  u16* ql  = (u16*)(ws + 24 * MB);
  u16* kh  = (u16*)(ws + 32 * MB);
  u16* kl  = (u16*)(ws + 40 * MB);
  u16* vh  = (u16*)(ws + 48 * MB);
  u16* ctx = (u16*)(ws + 56 * MB);
  u16* wh  = (u16*)(ws + 64 * MB);  // 3072x1024 hi (Wq,Wk,Wv)
  u16* wl  = (u16*)(ws + 70 * MB);  // 2048x1024 lo (Wq,Wk)
  u16* woh = (u16*)(ws + 74 * MB);  // 1024x1024 hi

  cvt_all<<<2048, 256, 0, stream>>>(x, Wq, Wk, Wv, Wo, xh, xl, wh, wl, woh);
  qkv_gemm<<<dim3(24, 32), 256, 0, stream>>>(xh, xl, wh, wl, qh, ql, kh, kl, vh);
  attn_kernel<<<dim3(32, 16, 2), 256, 0, stream>>>(qh, ql, kh, kl, vh, ctx);
  out_gemm<<<dim3(8, 64), 256, 0, stream>>>(ctx, woh, bo, out);
}

// Round 11
// 276.321 us; speedup vs baseline: 1.2489x; 1.2489x over previous
//
#include <hip/hip_runtime.h>

// InnerSelfAttention (sliding-window causal, WIN=256, unscaled QK^T) for MI355X.
// R11: UN-FUSE the QKV GEMM. The fused 3-region kernel carries an invariant
// ~385MB phantom WRITE_SIZE (R3/R4/R10) regardless of staging/order/epilogue;
// R1's split single-region GEMM measured exactly 16MB (clean). Revert to the
// R1-proven split structure (bf16x3 128^2 grid(8,32) per output), keeping only
// proven pieces: fused cvt_all, coalesced vh, R4 attn with LDS V-transpose.
// B=2 S=2048 E=1024 H=16 D=64 WIN=256.

typedef __bf16 bf16x8 __attribute__((ext_vector_type(8)));
typedef short s16x8 __attribute__((ext_vector_type(8)));
typedef float f32x4 __attribute__((ext_vector_type(4)));
typedef unsigned short u16;
typedef unsigned long long u64;

#define DEV __device__ __forceinline__

DEV u16 f2bf(float f) {  // RNE float->bf16
  unsigned u = __builtin_bit_cast(unsigned, f);
  u += 0x7FFFu + ((u >> 16) & 1u);
  return (u16)(u >> 16);
}
DEV float bf2f(u16 h) {
  unsigned u = ((unsigned)h) << 16;
  return __builtin_bit_cast(float, u);
}

#define MFMA16(a, b, c) __builtin_amdgcn_mfma_f32_16x16x32_bf16((a), (b), (c), 0, 0, 0)

// ---------------- fused convert / split kernel (proven R3..R10) -------------
__global__ __launch_bounds__(256) void cvt_all(
    const float* __restrict__ x, const float* __restrict__ Wq,
    const float* __restrict__ Wk, const float* __restrict__ Wv,
    const float* __restrict__ Wo, u16* __restrict__ xh, u16* __restrict__ xl,
    u16* __restrict__ wh, u16* __restrict__ wl, u16* __restrict__ woh) {
  for (int i = blockIdx.x * 256 + threadIdx.x; i < 2097152;
       i += gridDim.x * 256) {
    const float* src;
    u16 *dh, *dl = nullptr;
    int off;
    bool sp;
    if (i < 1048576) {
      src = x; off = i; dh = xh; dl = xl; sp = true;
    } else {
      int j = i - 1048576;
      int r = j >> 18;
      off = j & 262143;
      if (r == 0)      { src = Wq; dh = wh;           dl = wl;           sp = true; }
      else if (r == 1) { src = Wk; dh = wh + 1048576; dl = wl + 1048576; sp = true; }
      else if (r == 2) { src = Wv; dh = wh + 2097152; sp = false; }
      else             { src = Wo; dh = woh;          sp = false; }
    }
    f32x4 v = ((const f32x4*)src)[off];
    u64 ph = 0, pl = 0;
#pragma unroll
    for (int c = 0; c < 4; ++c) {
      u16 h = f2bf(v[c]);
      ph |= ((u64)h) << (16 * c);
      u16 l = f2bf(v[c] - bf2f(h));
      pl |= ((u64)l) << (16 * c);
    }
    ((u64*)dh)[off] = ph;
    if (sp) ((u64*)dl)[off] = pl;
  }
}

// ---------------- NT GEMM (R1-proven): C[4096][1024] = A . Bt^T -------------
// MODE 0: bf16x3 (A=xh/xl, B=Wh/Wl), epilogue split->hi,lo in [B,H,S,D]
// MODE 1: bf16,   epilogue bf16 -> [B,H,S,D] coalesced (V)
// MODE 2: bf16,   epilogue fp32 + bias -> out [M][N]
template <int MODE>
__global__ __launch_bounds__(256) void gemm_kernel(
    const u16* __restrict__ Ah, const u16* __restrict__ Al,
    const u16* __restrict__ Bh, const u16* __restrict__ Bl,
    u16* __restrict__ O1, u16* __restrict__ O2,
    const float* __restrict__ bias, float* __restrict__ Of) {
  constexpr bool SPLIT = (MODE == 0);
  constexpr int NS = SPLIT ? 2 : 1;
  constexpr int BKP = 40;  // 32 + 8 pad: 80B row stride -> 2-way bank alias
  __shared__ u16 sA[NS][128][BKP];
  __shared__ u16 sB[NS][128][BKP];

  const int tid = threadIdx.x;
  const int lane = tid & 63, w = tid >> 6;
  const int lr = lane & 15, lg = lane >> 4;
  const int wr = w >> 1, wc = w & 1;
  const int m0 = blockIdx.y * 128, n0 = blockIdx.x * 128;

  f32x4 acc[4][4];
#pragma unroll
  for (int i = 0; i < 4; ++i)
#pragma unroll
    for (int j = 0; j < 4; ++j)
#pragma unroll
      for (int e = 0; e < 4; ++e) acc[i][j][e] = 0.f;

  for (int k0 = 0; k0 < 1024; k0 += 32) {
// stage 128x32 bf16 tiles (reg-staged; padded LDS) — R1-proven
#pragma unroll
    for (int c = 0; c < 2; ++c) {
      int cid = c * 256 + tid;
      int row = cid >> 2, col8 = (cid & 3) * 8;
      size_t aoff = (size_t)(m0 + row) * 1024 + k0 + col8;
      size_t boff = (size_t)(n0 + row) * 1024 + k0 + col8;
      *(s16x8*)&sA[0][row][col8] = *(const s16x8*)&Ah[aoff];
      *(s16x8*)&sB[0][row][col8] = *(const s16x8*)&Bh[boff];
      if constexpr (SPLIT) {
        *(s16x8*)&sA[1][row][col8] = *(const s16x8*)&Al[aoff];
        *(s16x8*)&sB[1][row][col8] = *(const s16x8*)&Bl[boff];
      }
    }
    __syncthreads();

    bf16x8 fah[4], fbh[4], fal[4], fbl[4];
#pragma unroll
    for (int f = 0; f < 4; ++f) {
      fah[f] = *(const bf16x8*)&sA[0][wr * 64 + f * 16 + lr][lg * 8];
      fbh[f] = *(const bf16x8*)&sB[0][wc * 64 + f * 16 + lr][lg * 8];
      if constexpr (SPLIT) {
        fal[f] = *(const bf16x8*)&sA[1][wr * 64 + f * 16 + lr][lg * 8];
        fbl[f] = *(const bf16x8*)&sB[1][wc * 64 + f * 16 + lr][lg * 8];
      }
    }
#pragma unroll
    for (int i = 0; i < 4; ++i)
#pragma unroll
      for (int j = 0; j < 4; ++j) {
        acc[i][j] = MFMA16(fah[i], fbh[j], acc[i][j]);
        if constexpr (SPLIT) {
          acc[i][j] = MFMA16(fah[i], fbl[j], acc[i][j]);
          acc[i][j] = MFMA16(fal[i], fbh[j], acc[i][j]);
        }
      }
    __syncthreads();
  }

// epilogue. C layout (m89): col = lane&15, row = (lane>>4)*4 + e
#pragma unroll
  for (int i = 0; i < 4; ++i)
#pragma unroll
    for (int j = 0; j < 4; ++j)
#pragma unroll
      for (int e = 0; e < 4; ++e) {
        float v = acc[i][j][e];
        int mm = m0 + wr * 64 + i * 16 + lg * 4 + e;
        int nn = n0 + wc * 64 + j * 16 + lr;
        if constexpr (MODE == 0) {
          int bb = mm >> 11, ss = mm & 2047, hh = nn >> 6, dd = nn & 63;
          size_t idx = ((size_t)(bb * 16 + hh) * 2048 + ss) * 64 + dd;
          u16 h = f2bf(v);
          O1[idx] = h;
          O2[idx] = f2bf(v - bf2f(h));
        } else if constexpr (MODE == 1) {
          int bb = mm >> 11, ss = mm & 2047, hh = nn >> 6, dd = nn & 63;
          size_t idx = ((size_t)(bb * 16 + hh) * 2048 + ss) * 64 + dd;
          O1[idx] = f2bf(v);
        } else {
          Of[(size_t)mm * 1024 + nn] = v + bias[nn];
        }
      }
}

// ---------------- flash attention (R4-proven), 64-q blocks, 64-k tiles ------
// V arrives [B,H,S,D]; transposed into sVT[d][key] via LDS scatter at staging.
__global__ __launch_bounds__(256) void attn_kernel(
    const u16* __restrict__ qh, const u16* __restrict__ ql,
    const u16* __restrict__ kh, const u16* __restrict__ kl,
    const u16* __restrict__ vh, u16* __restrict__ ctx) {
  const int qt = blockIdx.x, hd = blockIdx.y, b = blockIdx.z;
  const int q0 = qt * 64;
  const int bh = b * 16 + hd;
  const int tid = threadIdx.x;
  const int lane = tid & 63, w = tid >> 6;
  const int lr = lane & 15, lg = lane >> 4;

  __shared__ u16 sKh[64][72];   // [key][d], 144B rows -> 2-way alias
  __shared__ u16 sKl[64][72];
  __shared__ u16 sVT[64][72];   // [d][key]
  __shared__ u16 sP[4][16][72]; // per-wave P tile [q][key]

  bf16x8 qfh[2], qfl[2];
  const size_t qbase = ((size_t)bh * 2048 + q0 + w * 16 + lr) * 64;
#pragma unroll
  for (int ks = 0; ks < 2; ++ks) {
    qfh[ks] = *(const bf16x8*)&qh[qbase + ks * 32 + lg * 8];
    qfl[ks] = *(const bf16x8*)&ql[qbase + ks * 32 + lg * 8];
  }

  float mrow[4], lrow[4];
  f32x4 cf[4];
#pragma unroll
  for (int e = 0; e < 4; ++e) { mrow[e] = -__builtin_inff(); lrow[e] = 0.f; }
#pragma unroll
  for (int nd = 0; nd < 4; ++nd)
#pragma unroll
    for (int e = 0; e < 4; ++e) cf[nd][e] = 0.f;

  const int t0 = (qt >= 4) ? qt - 4 : 0;
  for (int t = t0; t <= qt; ++t) {
    const int k0 = t * 64;
#pragma unroll
    for (int c = 0; c < 2; ++c) {
      int cid = c * 256 + tid;
      int row = cid >> 3, col8 = (cid & 7) * 8;
      size_t kidx = ((size_t)bh * 2048 + k0 + row) * 64 + col8;
      *(s16x8*)&sKh[row][col8] = *(const s16x8*)&kh[kidx];
      *(s16x8*)&sKl[row][col8] = *(const s16x8*)&kl[kidx];
      s16x8 vv = *(const s16x8*)&vh[kidx];  // coalesced V row read
#pragma unroll
      for (int j = 0; j < 8; ++j)           // LDS transpose scatter
        sVT[col8 + j][row] = (u16)vv[j];
    }
    __syncthreads();

    f32x4 sc[4];
#pragma unroll
    for (int nf = 0; nf < 4; ++nf)
#pragma unroll
      for (int e = 0; e < 4; ++e) sc[nf][e] = 0.f;
#pragma unroll
    for (int ks = 0; ks < 2; ++ks)
#pragma unroll
      for (int nf = 0; nf < 4; ++nf) {
        bf16x8 kbh = *(const bf16x8*)&sKh[nf * 16 + lr][ks * 32 + lg * 8];
        bf16x8 kbl = *(const bf16x8*)&sKl[nf * 16 + lr][ks * 32 + lg * 8];
        sc[nf] = MFMA16(qfh[ks], kbh, sc[nf]);
        sc[nf] = MFMA16(qfh[ks], kbl, sc[nf]);
        sc[nf] = MFMA16(qfl[ks], kbh, sc[nf]);
      }

    const bool masked = (k0 < q0 - 192) || (k0 >= q0);
    if (masked) {
#pragma unroll
      for (int nf = 0; nf < 4; ++nf) {
        int key = k0 + nf * 16 + lr;
#pragma unroll
        for (int e = 0; e < 4; ++e) {
          int qi = q0 + w * 16 + lg * 4 + e;
          if (key > qi || key + 256 <= qi) sc[nf][e] = -__builtin_inff();
        }
      }
    }

    float rm[4];
#pragma unroll
    for (int e = 0; e < 4; ++e)
      rm[e] = fmaxf(fmaxf(sc[0][e], sc[1][e]), fmaxf(sc[2][e], sc[3][e]));
#pragma unroll
    for (int off = 1; off < 16; off <<= 1)
#pragma unroll
      for (int e = 0; e < 4; ++e) rm[e] = fmaxf(rm[e], __shfl_xor(rm[e], off));

    float alpha[4], mu[4];
#pragma unroll
    for (int e = 0; e < 4; ++e) {
      float mn = fmaxf(mrow[e], rm[e]);
      bool ninf = (mn == -__builtin_inff());
      mu[e] = ninf ? 0.f : mn;
      alpha[e] = ninf ? 1.f : __expf(mrow[e] - mn);
      mrow[e] = mn;
    }
    float p[4][4], rs[4];
#pragma unroll
    for (int nf = 0; nf < 4; ++nf)
#pragma unroll
      for (int e = 0; e < 4; ++e) p[nf][e] = __expf(sc[nf][e] - mu[e]);
#pragma unroll
    for (int e = 0; e < 4; ++e) rs[e] = p[0][e] + p[1][e] + p[2][e] + p[3][e];
#pragma unroll
    for (int off = 1; off < 16; off <<= 1)
#pragma unroll
      for (int e = 0; e < 4; ++e) rs[e] += __shfl_xor(rs[e], off);
#pragma unroll
    for (int e = 0; e < 4; ++e) lrow[e] = lrow[e] * alpha[e] + rs[e];
#pragma unroll
    for (int nd = 0; nd < 4; ++nd)
#pragma unroll
      for (int e = 0; e < 4; ++e) cf[nd][e] *= alpha[e];

#pragma unroll
    for (int nf = 0; nf < 4; ++nf)
#pragma unroll
      for (int e = 0; e < 4; ++e)
        sP[w][lg * 4 + e][nf * 16 + lr] = f2bf(p[nf][e]);

#pragma unroll
    for (int ks = 0; ks < 2; ++ks) {
      bf16x8 pa = *(const bf16x8*)&sP[w][lr][ks * 32 + lg * 8];
#pragma unroll
      for (int nd = 0; nd < 4; ++nd) {
        bf16x8 vb = *(const bf16x8*)&sVT[nd * 16 + lr][ks * 32 + lg * 8];
        cf[nd] = MFMA16(pa, vb, cf[nd]);
      }
    }
    __syncthreads();
  }

#pragma unroll
  for (int nd = 0; nd < 4; ++nd)
#pragma unroll
    for (int e = 0; e < 4; ++e) {
      float v = cf[nd][e] / lrow[e];
      size_t o = ((size_t)(b * 2048 + q0 + w * 16 + lg * 4 + e)) * 1024 +
                 hd * 64 + nd * 16 + lr;
      ctx[o] = f2bf(v);
    }
}

// ---------------- launch ----------------
extern "C" void kernel_launch(void* const* d_in, const int* in_sizes, int n_in,
                              void* d_out, int out_size, void* d_ws, size_t ws_size,
                              hipStream_t stream) {
  (void)in_sizes; (void)n_in; (void)out_size; (void)ws_size;
  const float* x  = (const float*)d_in[0];
  const float* Wq = (const float*)d_in[1];
  const float* Wk = (const float*)d_in[2];
  const float* Wv = (const float*)d_in[3];
  const float* Wo = (const float*)d_in[4];
  const float* bo = (const float*)d_in[5];
  float* out = (float*)d_out;
  char* ws = (char*)d_ws;

  constexpr size_t MB = 1048576;
  u16* xh  = (u16*)(ws + 0 * MB);
  u16* xl  = (u16*)(ws + 8 * MB);
  u16* qh  = (u16*)(ws + 16 * MB);
  u16* ql  = (u16*)(ws + 24 * MB);
  u16* kh  = (u16*)(ws + 32 * MB);
  u16* kl  = (u16*)(ws + 40 * MB);
  u16* vh  = (u16*)(ws + 48 * MB);
  u16* ctx = (u16*)(ws + 56 * MB);
  u16* wh  = (u16*)(ws + 64 * MB);  // 3072x1024 hi (Wq,Wk,Wv stacked)
  u16* wl  = (u16*)(ws + 70 * MB);  // 2048x1024 lo (Wq,Wk stacked)
  u16* woh = (u16*)(ws + 74 * MB);  // 1024x1024 hi

  cvt_all<<<2048, 256, 0, stream>>>(x, Wq, Wk, Wv, Wo, xh, xl, wh, wl, woh);

  dim3 gg(8, 32), bb(256);
  gemm_kernel<0><<<gg, bb, 0, stream>>>(xh, xl, wh, wl, qh, ql, nullptr, nullptr);
  gemm_kernel<0><<<gg, bb, 0, stream>>>(xh, xl, wh + 1048576, wl + 1048576,
                                        kh, kl, nullptr, nullptr);
  gemm_kernel<1><<<gg, bb, 0, stream>>>(xh, nullptr, wh + 2097152, nullptr,
                                        vh, nullptr, nullptr, nullptr);
  attn_kernel<<<dim3(32, 16, 2), bb, 0, stream>>>(qh, ql, kh, kl, vh, ctx);
  gemm_kernel<2><<<gg, bb, 0, stream>>>(ctx, nullptr, woh, nullptr,
                                        nullptr, nullptr, bo, out);
}